// Round 8
// baseline (8627.091 us; speedup 1.0000x reference)
//
#include <hip/hip_runtime.h>
#include <cmath>

#define BB 8
#define NN 2048
#define CC 512
#define NITER 3
#define MP4 520     // f32 factor row stride (elements)
#define AUGCOL 512

// workspace layout (units: floats); f64 regions 8B-aligned
static constexpr size_t G_OFF   = 0;                          // f32 [B][3][C][C]
static constexpr size_t G_SZ    = (size_t)BB*3*CC*CC;
static constexpr size_t F32_OFF = G_OFF + G_SZ;               // f32 [B][C][MP4]
static constexpr size_t F32_SZ  = (size_t)BB*CC*MP4;
static constexpr size_t T32_OFF = F32_OFF + F32_SZ;           // f32 scratch
static constexpr size_t DF_OFF  = T32_OFF + F32_SZ;           // f64 [B][C][3]
static constexpr size_t DF_SZF  = (size_t)BB*CC*3*2;
static constexpr size_t E_OFF   = DF_OFF + DF_SZF;            // f64 [B][3][C]
static constexpr size_t E_SZF   = (size_t)BB*3*CC*2;
static constexpr size_t CON_OFF = E_OFF + E_SZF;              // f64 [B][C]
static constexpr size_t CON_SZF = (size_t)BB*CC*2;
static constexpr size_t LMD_OFF = CON_OFF + CON_SZF;          // f64 [B][C]
static constexpr size_t LMD_SZF = (size_t)BB*CC*2;
static constexpr size_t X0_OFF  = LMD_OFF + LMD_SZF;          // f64 [B][C]
static constexpr size_t X0_SZF  = (size_t)BB*CC*2;
static constexpr size_t PERM_OFF= X0_OFF + X0_SZF;            // int [B][8][C]
static constexpr size_t PERM_SZ = (size_t)BB*8*CC;
static constexpr size_t PART_OFF= PERM_OFF + PERM_SZ;         // f32 [8][B][6144]

// ---------------------------------------------------------------------------
// G (f32, f64 math); diff0 (f64); zero lambda.  grid (512 c, 8 b) x 256
__global__ void k_gbuild(const float* __restrict__ pos, const float* __restrict__ mas,
                         const float* __restrict__ jacp, const int* __restrict__ pi,
                         const int* __restrict__ pj, float* __restrict__ ws)
{
    const int c = blockIdx.x, b = blockIdx.y, t = threadIdx.x;
    const int i = pi[c], j = pj[c];
    const double im = 1.0 / (double)mas[b*NN + i];
    const double jm = 1.0 / (double)mas[b*NN + j];
    float* G = ws + G_OFF;
    const float* Ji = jacp + ((size_t)b*CC*NN + i)*3;
    const float* Jj = jacp + ((size_t)b*CC*NN + j)*3;
    for (int cp = t; cp < CC; cp += 256){
        const size_t o = (size_t)cp*NN*3;
        const size_t gb = ((size_t)(b*3)*CC + c)*CC + cp;
        G[gb]                   = (float)((double)Ji[o+0]*im - (double)Jj[o+0]*jm);
        G[gb + (size_t)CC*CC]   = (float)((double)Ji[o+1]*im - (double)Jj[o+1]*jm);
        G[gb + (size_t)2*CC*CC] = (float)((double)Ji[o+2]*im - (double)Jj[o+2]*jm);
    }
    if (t == 0){
        double* df = (double*)(ws + DF_OFF) + ((size_t)b*CC + c)*3;
        for (int d = 0; d < 3; ++d)
            df[d] = (double)pos[((size_t)b*NN+i)*3+d] - (double)pos[((size_t)b*NN+j)*3+d];
    }
    if (c == 0){
        double* l = (double*)(ws + LMD_OFF) + (size_t)b*CC;
        l[t] = 0.0; l[t+256] = 0.0;
    }
}

// ---------------------------------------------------------------------------
// f32 pivoted elimination step, K compile-time (template forces full unroll;
// rolled loops around r[] spilled the array to scratch in R3/R4/R5).
template<int K>
__device__ __forceinline__ void panel_step(float (&r)[64], int& mypos, const bool h,
                                           const int t, float* __restrict__ bufB,
                                           float* __restrict__ wv, int* __restrict__ wi,
                                           int* __restrict__ sh_lw)
{
    const float v = (h && mypos >= K) ? fabsf(r[K]) : -1.0f;
    float vmax = v;
    #pragma unroll
    for (int off = 32; off; off >>= 1){
        const float o = __shfl_xor(vmax, off);
        vmax = fmaxf(vmax, o);
    }
    int idx = (v >= 0.0f && v == vmax) ? t : (1 << 20);
    #pragma unroll
    for (int off = 32; off; off >>= 1){
        const int o = __shfl_xor(idx, off);
        idx = min(idx, o);
    }
    if ((t & 63) == 0){ wv[t>>6] = vmax; wi[t>>6] = idx; }
    __syncthreads();
    float gv = wv[0];
    #pragma unroll
    for (int w = 1; w < 8; ++w) gv = fmaxf(gv, wv[w]);
    int wp = 1 << 20;
    #pragma unroll
    for (int w = 0; w < 8; ++w) if (wv[w] == gv) wp = min(wp, wi[w]);
    if (t == wp){
        *sh_lw = mypos;
        #pragma unroll
        for (int j = K; j < 64; ++j) bufB[j] = r[j];
    }
    __syncthreads();
    const int lw = *sh_lw;
    if (t == wp) mypos = K;
    else if (mypos == K) mypos = lw;
    if (h && mypos > K){
        const float pv = bufB[K];
        const float ml = r[K] / pv;
        r[K] = ml;
        #pragma unroll
        for (int j = K + 1; j < 64; ++j) r[j] = fmaf(-ml, bufB[j], r[j]);
    }
}

template<int K>
__device__ __forceinline__ void panel_rec(float (&r)[64], int& mypos, const bool h,
                                          const int t, float* __restrict__ bufB,
                                          float* __restrict__ wv, int* __restrict__ wi,
                                          int* __restrict__ sh_lw)
{
    if constexpr (K < 64){
        panel_step<K>(r, mypos, h, t, bufB, wv, wi, sh_lw);
        panel_rec<K + 1>(r, mypos, h, t, bufB, wv, wi, sh_lw);
    }
}

// Thread-per-column forward substitution (unit lower L from LDS, broadcast
// reads). Template-static x[] indices keep the column in registers.
template<int I>
__device__ __forceinline__ void fsub_rec(float (&x)[64], const float* __restrict__ Ls)
{
    if constexpr (I < 64){
        float acc = x[I];
        #pragma unroll
        for (int j = 0; j < I; ++j) acc = fmaf(-Ls[I*65 + j], x[j], acc);
        x[I] = acc;
        fsub_rec<I + 1>(x, Ls);
    }
}

// ---------------------------------------------------------------------------
// ONE WG PER BATCH does the whole 3-iteration Newton solve. Zero grid syncs;
// F/T stay in the WG's XCD L2. R7 post-mortem: fused coop kernel throttled
// occupancy to 1 blk/CU and paid ~83 grid.syncs; the batch solves are
// independent, so give each its own CU and only __syncthreads.
// grid (8 b) x 512
__global__ __launch_bounds__(512, 1) void k_solve(const float* __restrict__ dtm,
                                                  const float* __restrict__ d0v,
                                                  float* __restrict__ ws)
{
    const int b = blockIdx.x, t = threadIdx.x;
    __shared__ alignas(16) float sh[9216];

    float* F = ws + F32_OFF + (size_t)b*CC*MP4;
    float* T = ws + T32_OFF + (size_t)b*CC*MP4;
    const float* G0 = ws + G_OFF + ((size_t)(b*3))*CC*CC;
    const float* G1 = G0 + (size_t)CC*CC;
    const float* G2 = G1 + (size_t)CC*CC;
    double* lmd  = (double*)(ws + LMD_OFF) + (size_t)b*CC;
    double* e0g  = (double*)(ws + E_OFF)  + (size_t)b*3*CC;
    double* e1g  = e0g + CC;
    double* e2g  = e0g + 2*CC;
    double* cong = (double*)(ws + CON_OFF) + (size_t)b*CC;
    double* x0g  = (double*)(ws + X0_OFF)  + (size_t)b*CC;
    const double* df = (const double*)(ws + DF_OFF) + ((size_t)b*CC + t)*3;
    const double dt = (double)dtm[b], dt2 = dt*dt, s = -2.0*dt2;
    const double d0t = (double)d0v[t];

    const float4* g0v = (const float4*)(G0 + (size_t)t*CC);
    const float4* g1v = (const float4*)(G1 + (size_t)t*CC);
    const float4* g2v = (const float4*)(G2 + (size_t)t*CC);

    for (int it = 0; it < NITER; ++it){
        // ---------------- build: row-per-thread GEMV + jac row ----------------
        {
            double* lamS = (double*)sh;          // 512 f64
            lamS[t] = lmd[t];
            __syncthreads();
            double y0 = 0, y1 = 0, y2 = 0;
            for (int q = 0; q < 128; ++q){
                const float4 a0 = g0v[q], a1 = g1v[q], a2 = g2v[q];
                const double l0 = lamS[q*4], l1 = lamS[q*4+1];
                const double l2 = lamS[q*4+2], l3 = lamS[q*4+3];
                y0 += (double)a0.x*l0 + (double)a0.y*l1 + (double)a0.z*l2 + (double)a0.w*l3;
                y1 += (double)a1.x*l0 + (double)a1.y*l1 + (double)a1.z*l2 + (double)a1.w*l3;
                y2 += (double)a2.x*l0 + (double)a2.y*l1 + (double)a2.z*l2 + (double)a2.w*l3;
            }
            const double e0 = df[0] - dt2*y0;
            const double e1 = df[1] - dt2*y1;
            const double e2 = df[2] - dt2*y2;
            const double con = e0*e0 + e1*e1 + e2*e2 - d0t;
            e0g[t] = e0; e1g[t] = e1; e2g[t] = e2; cong[t] = con;
            float4* Fv = (float4*)(F + (size_t)t*MP4);
            for (int q = 0; q < 128; ++q){
                const float4 a0 = g0v[q], a1 = g1v[q], a2 = g2v[q];
                float4 o;
                o.x = (float)(s*(e0*(double)a0.x + e1*(double)a1.x + e2*(double)a2.x));
                o.y = (float)(s*(e0*(double)a0.y + e1*(double)a1.y + e2*(double)a2.y));
                o.z = (float)(s*(e0*(double)a0.z + e1*(double)a1.z + e2*(double)a2.z));
                o.w = (float)(s*(e0*(double)a0.w + e1*(double)a1.w + e2*(double)a2.w));
                Fv[q] = o;
            }
            F[(size_t)t*MP4 + AUGCOL] = (float)con;
            __syncthreads();
        }

        // ---------------- blocked LU with partial pivoting ----------------
        for (int kb = 0; kb < 8; ++kb){
            const int base = kb*64, m = CC - base;
            const int cs0 = base + 64;               // first trailing col (kb=7 -> aug)
            const int ncols = 512 - cs0 + 1;         // contiguous [(kb+1)*64 .. 512]
            // ---- panel ----
            {
                float* bufB = sh;
                float* wv   = sh + 64;
                int*   wi   = (int*)(sh + 72);
                int*   slw  = (int*)(sh + 80);
                const bool h = (t < m);
                float r[64];
                if (h){
                    const float* sp = F + (size_t)(base + t)*MP4 + base;
                    #pragma unroll
                    for (int j = 0; j < 64; ++j) r[j] = sp[j];
                }
                int mypos = t;
                __syncthreads();
                panel_rec<0>(r, mypos, h, t, bufB, wv, wi, slw);
                if (h){
                    float* dp = F + (size_t)(base + mypos)*MP4 + base;
                    #pragma unroll
                    for (int j = 0; j < 64; ++j) dp[j] = r[j];
                    ((int*)(ws + PERM_OFF))[(b*8 + kb)*CC + mypos] = t;
                }
                __syncthreads();
            }
            // ---- stage L + perm ----
            float* Ls = sh + 1024;                   // [64][65]
            int* permS = (int*)(sh + 5184);          // [64]
            for (int idx = t; idx < 4096; idx += 512)
                Ls[(idx>>6)*65 + (idx&63)] = F[(size_t)(base + (idx>>6))*MP4 + base + (idx&63)];
            const int* permG = (const int*)(ws + PERM_OFF) + (b*8 + kb)*CC;
            if (t < 64) permS[t] = permG[t];
            __syncthreads();
            // ---- permute below-panel rows into T (all trailing cols) ----
            for (int l = 64 + (t>>6); l < m; l += 8){
                const size_t srcr = (size_t)(base + permG[l])*MP4 + cs0;
                const size_t dstr = (size_t)(base + l)*MP4 + cs0;
                for (int c = (t&63); c < ncols; c += 64)
                    T[dstr + c] = F[srcr + c];
            }
            // ---- TRSM: gather column (reads F BEFORE barrier), solve, write ----
            float x[64];
            const bool act = (t < ncols);
            const int col = cs0 + t;
            if (act){
                #pragma unroll
                for (int l = 0; l < 64; ++l)
                    x[l] = F[(size_t)(base + permS[l])*MP4 + col];
            }
            __syncthreads();    // all F reads (T-copy + gather) precede U12 writes
            if (act){
                fsub_rec<1>(x, Ls);
                #pragma unroll
                for (int l = 0; l < 64; ++l)
                    F[(size_t)(base + l)*MP4 + col] = x[l];
            }
            // ---- trailing GEMM: F = T - L21*U12 ----
            if (kb < 7){
                float* LTc = sh;            // [64][66]  LTc[kk][r]
                float* Uc  = sh + 4352;     // [64][68]  Uc[kk][c]
                for (int rt = 0; rt < 7 - kb; ++rt){
                    const int gr0 = base + 64 + rt*64;
                    __syncthreads();
                    for (int idx = t; idx < 4096; idx += 512)
                        LTc[(idx&63)*66 + (idx>>6)] = F[(size_t)(gr0 + (idx>>6))*MP4 + base + (idx&63)];
                    for (int ct = 0; ct <= 7 - kb; ++ct){
                        const int cs = cs0 + ct*64;
                        const int W = min(64, ncols - ct*64);
                        __syncthreads();
                        for (int idx = t; idx < 4096; idx += 512){
                            const int rr = idx >> 6, ccc = idx & 63;
                            Uc[rr*68 + ccc] = (ccc < W) ? F[(size_t)(base + rr)*MP4 + cs + ccc] : 0.f;
                        }
                        __syncthreads();
                        const int r0 = (t >> 4)*2, c0 = (t & 15)*4;
                        float a00=0,a01=0,a02=0,a03=0,a10=0,a11=0,a12=0,a13=0;
                        for (int kk = 0; kk < 64; ++kk){
                            const float2 lv = *(const float2*)&LTc[kk*66 + r0];
                            const float4 uv = *(const float4*)&Uc[kk*68 + c0];
                            a00 = fmaf(lv.x, uv.x, a00); a01 = fmaf(lv.x, uv.y, a01);
                            a02 = fmaf(lv.x, uv.z, a02); a03 = fmaf(lv.x, uv.w, a03);
                            a10 = fmaf(lv.y, uv.x, a10); a11 = fmaf(lv.y, uv.y, a11);
                            a12 = fmaf(lv.y, uv.z, a12); a13 = fmaf(lv.y, uv.w, a13);
                        }
                        const float accs[2][4] = {{a00,a01,a02,a03},{a10,a11,a12,a13}};
                        #pragma unroll
                        for (int i = 0; i < 2; ++i)
                            #pragma unroll
                            for (int j = 0; j < 4; ++j){
                                const int c2 = c0 + j;
                                if (c2 < W){
                                    const size_t o = (size_t)(gr0 + r0 + i)*MP4 + cs + c2;
                                    F[o] = T[o] - accs[i][j];
                                }
                            }
                    }
                }
            }
            __syncthreads();
        }

        // ---------------- backsub -> x0 ----------------
        {
            float* y  = sh;                 // 512
            float* Ud = sh + 512;           // [64][65]
            y[t] = F[(size_t)t*MP4 + AUGCOL];
            __syncthreads();
            for (int sb = 7; sb >= 0; --sb){
                const int rb = sb*64;
                for (int idx = t; idx < 4096; idx += 512)
                    Ud[(idx>>6)*65 + (idx&63)] = F[(size_t)(rb + (idx>>6))*MP4 + rb + (idx&63)];
                __syncthreads();
                if (t < 64){
                    float yv = y[rb + t];
                    for (int kk = 63; kk >= 0; --kk){
                        float xk = __shfl(yv, kk);
                        xk = xk / Ud[kk*65 + kk];
                        if (t == kk) yv = xk;
                        else if (t < kk) yv = fmaf(-Ud[t*65 + kk], xk, yv);
                    }
                    y[rb + t] = yv;
                }
                __syncthreads();
                if (t < rb){
                    const float* Fr = F + (size_t)t*MP4 + rb;
                    float sacc = 0.f;
                    for (int j = 0; j < 64; ++j) sacc = fmaf(Fr[j], y[rb + j], sacc);
                    y[t] -= sacc;
                }
                __syncthreads();
            }
            x0g[t] = (double)y[t];
        }
        __syncthreads();

        // ---------------- resid (separable, f64): r = con - s*Sum e_d.*(G_d x0)
        {
            double* xS = (double*)sh;       // 512 f64 (sh[0..1023])
            xS[t] = x0g[t];
            __syncthreads();
            double q0 = 0, q1 = 0, q2 = 0;
            for (int q = 0; q < 128; ++q){
                const float4 a0 = g0v[q], a1 = g1v[q], a2 = g2v[q];
                const double v0 = xS[q*4], v1 = xS[q*4+1], v2 = xS[q*4+2], v3 = xS[q*4+3];
                q0 += (double)a0.x*v0 + (double)a0.y*v1 + (double)a0.z*v2 + (double)a0.w*v3;
                q1 += (double)a1.x*v0 + (double)a1.y*v1 + (double)a1.z*v2 + (double)a1.w*v3;
                q2 += (double)a2.x*v0 + (double)a2.y*v1 + (double)a2.z*v2 + (double)a2.w*v3;
            }
            const double rv = cong[t] - s*(e0g[t]*q0 + e1g[t]*q1 + e2g[t]*q2);
            sh[1024 + t] = (float)rv;       // rsolve input (disjoint from xS)
            __syncthreads();
        }

        // ---------------- rsolve: d = U^-1 L^-1 P r;  lmd -= x0 + d ----------
        {
            float* y  = sh + 1024;          // 512
            float* Ls2 = sh + 1536;         // [64][65]
            for (int kb2 = 0; kb2 < 8; ++kb2){
                const int base2 = kb2*64, m2 = CC - base2;
                const int* perm = (const int*)(ws + PERM_OFF) + (b*8 + kb2)*CC;
                float v = 0.f;
                if (t < m2) v = y[base2 + perm[t]];
                __syncthreads();
                if (t < m2) y[base2 + t] = v;
                for (int idx = t; idx < 4096; idx += 512)
                    Ls2[(idx>>6)*65 + (idx&63)] = F[(size_t)(base2 + (idx>>6))*MP4 + base2 + (idx&63)];
                __syncthreads();
                if (t < 64){
                    float yv = y[base2 + t];
                    for (int kk = 0; kk < 63; ++kk){
                        const float xk = __shfl(yv, kk);
                        if (t > kk) yv = fmaf(-Ls2[t*65 + kk], xk, yv);
                    }
                    y[base2 + t] = yv;
                }
                __syncthreads();
                if (t >= 64 && t < m2){
                    const float* Fr = F + (size_t)(base2 + t)*MP4 + base2;
                    float sacc = 0.f;
                    for (int ss = 0; ss < 64; ++ss) sacc = fmaf(Fr[ss], y[base2 + ss], sacc);
                    y[base2 + t] -= sacc;
                }
                __syncthreads();
            }
            for (int sb = 7; sb >= 0; --sb){
                const int rb = sb*64;
                for (int idx = t; idx < 4096; idx += 512)
                    Ls2[(idx>>6)*65 + (idx&63)] = F[(size_t)(rb + (idx>>6))*MP4 + rb + (idx&63)];
                __syncthreads();
                if (t < 64){
                    float yv = y[rb + t];
                    for (int kk = 63; kk >= 0; --kk){
                        float xk = __shfl(yv, kk);
                        xk = xk / Ls2[kk*65 + kk];
                        if (t == kk) yv = xk;
                        else if (t < kk) yv = fmaf(-Ls2[t*65 + kk], xk, yv);
                    }
                    y[rb + t] = yv;
                }
                __syncthreads();
                if (t < rb){
                    const float* Fr = F + (size_t)t*MP4 + rb;
                    float sacc = 0.f;
                    for (int j = 0; j < 64; ++j) sacc = fmaf(Fr[j], y[rb + j], sacc);
                    y[t] -= sacc;
                }
                __syncthreads();
            }
            lmd[t] -= x0g[t] + (double)y[t];
        }
        __syncthreads();
    }
}

// ---------------------------------------------------------------------------
// Split-K partial of sum_c lmd*jacp (f64 accum, f32 store).
// grid (24 nb, 8 b, 8 kc) x 256
__global__ void k_frc(const float* __restrict__ jacp, float* __restrict__ ws)
{
    const int nb = blockIdx.x, b = blockIdx.y, kc = blockIdx.z, t = threadIdx.x;
    const int nd = nb*256 + t;
    const double* l = (const double*)(ws + LMD_OFF) + (size_t)b*CC + kc*64;
    const float* J = jacp + ((size_t)(b*CC + kc*64))*NN*3 + nd;
    double acc = 0.0;
    for (int c2 = 0; c2 < 64; ++c2) acc = fma(l[c2], (double)J[(size_t)c2*NN*3], acc);
    ws[PART_OFF + ((size_t)kc*8 + b)*6144 + nd] = (float)acc;
}

// ---------------------------------------------------------------------------
// Combine partials, write pos_new, mom_new, lmd.  grid (208) x 256
__global__ void k_out(const float* __restrict__ pos, const float* __restrict__ mom,
                      const float* __restrict__ mas, const float* __restrict__ dtm,
                      const float* __restrict__ ws, float* __restrict__ out)
{
    const int wg = blockIdx.x, t = threadIdx.x;
    if (wg < 192){
        const int b = wg / 24, nb = wg % 24;
        const int nd = nb*256 + t;
        float sacc = 0.f;
        for (int kc = 0; kc < 8; ++kc) sacc += ws[PART_OFF + ((size_t)kc*8 + b)*6144 + nd];
        const float frc = -sacc;
        const int n = nd / 3;
        const float dt = dtm[b], dt2 = dt*dt;
        out[(size_t)b*6144 + nd]         = pos[(size_t)b*6144 + nd] + frc / mas[b*NN + n] * dt2;
        out[49152 + (size_t)b*6144 + nd] = mom[(size_t)b*6144 + nd] + frc * dt;
    } else {
        const int idx = (wg - 192)*256 + t;      // 0..4095
        out[98304 + idx] = (float)(((const double*)(ws + LMD_OFF))[idx]);
    }
}

// ---------------------------------------------------------------------------
extern "C" void kernel_launch(void* const* d_in, const int* in_sizes, int n_in,
                              void* d_out, int out_size, void* d_ws, size_t ws_size,
                              hipStream_t stream)
{
    (void)in_sizes; (void)n_in; (void)out_size; (void)ws_size;
    const float* pos  = (const float*)d_in[0];
    const float* mom  = (const float*)d_in[1];
    const float* mas  = (const float*)d_in[2];
    const float* dtm  = (const float*)d_in[3];
    const float* jacp = (const float*)d_in[4];
    const int*   pi   = (const int*)d_in[5];
    const int*   pj   = (const int*)d_in[6];
    const float* d0v  = (const float*)d_in[7];
    float* ws  = (float*)d_ws;
    float* out = (float*)d_out;

    k_gbuild<<<dim3(CC, BB), 256, 0, stream>>>(pos, mas, jacp, pi, pj, ws);
    k_solve<<<dim3(BB), 512, 0, stream>>>(dtm, d0v, ws);
    k_frc<<<dim3(24, BB, 8), 256, 0, stream>>>(jacp, ws);
    k_out<<<dim3(208), 256, 0, stream>>>(pos, mom, mas, dtm, ws, out);
}